// Round 1
// baseline (641.554 us; speedup 1.0000x reference)
//
#include <hip/hip_runtime.h>
#include <math.h>

typedef float f32x4 __attribute__((ext_vector_type(4)));
typedef unsigned short ushort8 __attribute__((ext_vector_type(8)));
typedef __bf16 bf16x8 __attribute__((ext_vector_type(8)));

__device__ __forceinline__ unsigned short f2bf(float x) {
  union { float f; unsigned u; } v; v.f = x;
  unsigned r = v.u + 0x7FFFu + ((v.u >> 16) & 1u);   // RNE
  return (unsigned short)(r >> 16);
}

__device__ __forceinline__ f32x4 mfma16(ushort8 a, ushort8 b, f32x4 c) {
  return __builtin_amdgcn_mfma_f32_16x16x32_bf16(
      __builtin_bit_cast(bf16x8, a), __builtin_bit_cast(bf16x8, b), c, 0, 0, 0);
}

// ---------------------------------------------------------------------------
// GEMM: C[M,N] = A[M,K] @ B[K,N] + bias[N], optional ReLU.
// 128x128 tile, BK=64, 256 threads = 4 waves (2x2), mfma_f32_16x16x32_bf16.
// LDS bf16, XOR swizzle byte ^= (row&7)<<4 within 128B rows (2-way max).
// ---------------------------------------------------------------------------
__global__ __launch_bounds__(256) void gemm_bias_kernel(
    const float* __restrict__ A, const float* __restrict__ Bw,
    const float* __restrict__ bias, float* __restrict__ C,
    int M, int N, int K, int relu)
{
  __shared__ __align__(16) unsigned short As[128 * 64];  // [m][k]
  __shared__ __align__(16) unsigned short Bs[128 * 64];  // [n][k]  (B^T)
  const int bn = blockIdx.x, bm = blockIdx.y;
  const int t = threadIdx.x;
  const int lane = t & 63, w = t >> 6, wm = w >> 1, wn = w & 1;
  const int l4 = lane & 15, lg = lane >> 4;

  f32x4 acc[4][4];
#pragma unroll
  for (int i = 0; i < 4; ++i)
#pragma unroll
    for (int j = 0; j < 4; ++j) acc[i][j] = f32x4{0.f, 0.f, 0.f, 0.f};

  const int a_kc = t & 7, a_r0 = t >> 3;     // A staging: 8 k-chunks x 32 rows
  const int b_n = t & 127, b_kh = t >> 7;    // B staging: 128 n x 2 k-halves

  const int nkt = K >> 6;
  for (int kt = 0; kt < nkt; ++kt) {
    __syncthreads();
    {  // stage A tile [128][64]
      const float* Ab = A + (size_t)(bm * 128) * K + (size_t)kt * 64;
#pragma unroll
      for (int i = 0; i < 4; ++i) {
        int r = a_r0 + 32 * i;
        const float* src = Ab + (size_t)r * K + a_kc * 8;
        float4 f0 = *reinterpret_cast<const float4*>(src);
        float4 f1 = *reinterpret_cast<const float4*>(src + 4);
        ushort8 v;
        v[0] = f2bf(f0.x); v[1] = f2bf(f0.y); v[2] = f2bf(f0.z); v[3] = f2bf(f0.w);
        v[4] = f2bf(f1.x); v[5] = f2bf(f1.y); v[6] = f2bf(f1.z); v[7] = f2bf(f1.w);
        int off = r * 128 + ((a_kc * 16) ^ ((r & 7) << 4));
        *reinterpret_cast<ushort8*>((char*)As + off) = v;
      }
    }
    {  // stage B^T tile [128 n][64 k]; global reads coalesced along n
      const float* Bb = Bw + (size_t)(kt * 64) * N + bn * 128 + b_n;
#pragma unroll
      for (int i = 0; i < 4; ++i) {
        int k0 = b_kh * 32 + i * 8;
        ushort8 v;
#pragma unroll
        for (int j = 0; j < 8; ++j) v[j] = f2bf(Bb[(size_t)(k0 + j) * N]);
        int off = b_n * 128 + ((k0 * 2) ^ ((b_n & 7) << 4));
        *reinterpret_cast<ushort8*>((char*)Bs + off) = v;
      }
    }
    __syncthreads();
#pragma unroll
    for (int ks = 0; ks < 2; ++ks) {
      const int kb = (ks * 32 + lg * 8) * 2;
      ushort8 af[4], bfr[4];
#pragma unroll
      for (int mi = 0; mi < 4; ++mi) {
        int r = wm * 64 + mi * 16 + l4;
        af[mi] = *reinterpret_cast<const ushort8*>((const char*)As + r * 128 + (kb ^ ((r & 7) << 4)));
      }
#pragma unroll
      for (int ni = 0; ni < 4; ++ni) {
        int r = wn * 64 + ni * 16 + l4;
        bfr[ni] = *reinterpret_cast<const ushort8*>((const char*)Bs + r * 128 + (kb ^ ((r & 7) << 4)));
      }
#pragma unroll
      for (int mi = 0; mi < 4; ++mi)
#pragma unroll
        for (int ni = 0; ni < 4; ++ni)
          acc[mi][ni] = mfma16(af[mi], bfr[ni], acc[mi][ni]);
    }
  }
  // epilogue: C row = (lane>>4)*4+j, col = lane&15 (verified C/D layout)
#pragma unroll
  for (int mi = 0; mi < 4; ++mi)
#pragma unroll
    for (int ni = 0; ni < 4; ++ni) {
      int col = bn * 128 + wn * 64 + ni * 16 + l4;
      float bia = bias[col];
#pragma unroll
      for (int j = 0; j < 4; ++j) {
        int row = bm * 128 + wm * 64 + mi * 16 + lg * 4 + j;
        float vv = acc[mi][ni][j] + bia;
        if (relu) vv = fmaxf(vv, 0.f);
        C[(size_t)row * N + col] = vv;
      }
    }
}

// ---------------------------------------------------------------------------
// Flash attention. Q,K,V are [B*S, D] f32 with head h at cols h*64..h*64+63.
// Block = (qt, h, b): 64 q-rows, 4 waves x 16 q-rows. Online softmax in f32.
// ---------------------------------------------------------------------------
constexpr int kBz = 4, kS = 1024, kD = 1024, kDH = 64;

__global__ __launch_bounds__(256) void attn_kernel(
    const float* __restrict__ Qg, const float* __restrict__ Kg,
    const float* __restrict__ Vg, const int* __restrict__ maskg,
    float* __restrict__ Og)
{
  __shared__ __align__(16) unsigned short Qs[64 * 64];   // [q][d]
  __shared__ __align__(16) unsigned short Ks[64 * 64];   // [key][d]
  __shared__ __align__(16) unsigned short VTs[64 * 64];  // [d][key]
  __shared__ __align__(16) unsigned short Ps[4 * 16 * 64];  // per-wave [q16][key64]
  const int qt = blockIdx.x, h = blockIdx.y, b = blockIdx.z;
  const int t = threadIdx.x, lane = t & 63, w = t >> 6;
  const int l4 = lane & 15, lg = lane >> 4;

  {  // stage Q once (pre-scaled by 1/sqrt(64))
    int r = t >> 2, c0 = (t & 3) * 16;
    const float* src = Qg + ((size_t)(b * kS + qt * 64 + r)) * kD + h * kDH + c0;
#pragma unroll
    for (int hf = 0; hf < 2; ++hf) {
      float4 f0 = *reinterpret_cast<const float4*>(src + hf * 8);
      float4 f1 = *reinterpret_cast<const float4*>(src + hf * 8 + 4);
      ushort8 v;
      v[0] = f2bf(f0.x * 0.125f); v[1] = f2bf(f0.y * 0.125f);
      v[2] = f2bf(f0.z * 0.125f); v[3] = f2bf(f0.w * 0.125f);
      v[4] = f2bf(f1.x * 0.125f); v[5] = f2bf(f1.y * 0.125f);
      v[6] = f2bf(f1.z * 0.125f); v[7] = f2bf(f1.w * 0.125f);
      int c = c0 + hf * 8;
      int off = r * 128 + ((c * 2) ^ ((r & 7) << 4));
      *reinterpret_cast<ushort8*>((char*)Qs + off) = v;
    }
  }

  float m_r[4], l_r[4];
  f32x4 o[4];
#pragma unroll
  for (int j = 0; j < 4; ++j) { m_r[j] = -1e30f; l_r[j] = 0.f; }
#pragma unroll
  for (int di = 0; di < 4; ++di) o[di] = f32x4{0.f, 0.f, 0.f, 0.f};

  for (int kt = 0; kt < kS / 64; ++kt) {
    __syncthreads();
    {  // stage K tile
      int r = t >> 2, c0 = (t & 3) * 16;
      const float* src = Kg + ((size_t)(b * kS + kt * 64 + r)) * kD + h * kDH + c0;
#pragma unroll
      for (int hf = 0; hf < 2; ++hf) {
        float4 f0 = *reinterpret_cast<const float4*>(src + hf * 8);
        float4 f1 = *reinterpret_cast<const float4*>(src + hf * 8 + 4);
        ushort8 v;
        v[0] = f2bf(f0.x); v[1] = f2bf(f0.y); v[2] = f2bf(f0.z); v[3] = f2bf(f0.w);
        v[4] = f2bf(f1.x); v[5] = f2bf(f1.y); v[6] = f2bf(f1.z); v[7] = f2bf(f1.w);
        int c = c0 + hf * 8;
        int off = r * 128 + ((c * 2) ^ ((r & 7) << 4));
        *reinterpret_cast<ushort8*>((char*)Ks + off) = v;
      }
    }
    {  // stage V transposed [d][key]
      int key = t >> 2, c0 = (t & 3) * 16;
      const float* src = Vg + ((size_t)(b * kS + kt * 64 + key)) * kD + h * kDH + c0;
      float4 f0 = *reinterpret_cast<const float4*>(src);
      float4 f1 = *reinterpret_cast<const float4*>(src + 4);
      float4 f2 = *reinterpret_cast<const float4*>(src + 8);
      float4 f3 = *reinterpret_cast<const float4*>(src + 12);
      float tmp[16] = {f0.x, f0.y, f0.z, f0.w, f1.x, f1.y, f1.z, f1.w,
                       f2.x, f2.y, f2.z, f2.w, f3.x, f3.y, f3.z, f3.w};
#pragma unroll
      for (int i = 0; i < 16; ++i) {
        int dh = c0 + i;
        int off = dh * 128 + ((key * 2) ^ ((dh & 7) << 4));
        *reinterpret_cast<unsigned short*>((char*)VTs + off) = f2bf(tmp[i]);
      }
    }
    __syncthreads();

    // S = Q K^T  (wave's 16 q-rows x 64 keys)
    f32x4 sc[4];
#pragma unroll
    for (int ni = 0; ni < 4; ++ni) sc[ni] = f32x4{0.f, 0.f, 0.f, 0.f};
#pragma unroll
    for (int ks = 0; ks < 2; ++ks) {
      const int kb = (ks * 32 + lg * 8) * 2;
      int qr = w * 16 + l4;
      ushort8 a = *reinterpret_cast<const ushort8*>((const char*)Qs + qr * 128 + (kb ^ ((qr & 7) << 4)));
#pragma unroll
      for (int ni = 0; ni < 4; ++ni) {
        int kr = ni * 16 + l4;
        ushort8 bb = *reinterpret_cast<const ushort8*>((const char*)Ks + kr * 128 + (kb ^ ((kr & 7) << 4)));
        sc[ni] = mfma16(a, bb, sc[ni]);
      }
    }

    // mask + online softmax (C layout: row=lg*4+j (q), col=ni*16+l4 (key))
    const int qbase = qt * 64 + w * 16;
    float pmax[4];
#pragma unroll
    for (int j = 0; j < 4; ++j) {
      int qrow = qbase + lg * 4 + j;
      const int* mrow = maskg + ((size_t)b * kS + qrow) * kS + kt * 64;
#pragma unroll
      for (int ni = 0; ni < 4; ++ni) {
        float mv = (float)mrow[ni * 16 + l4];
        sc[ni][j] += (1.0f - mv) * (-1e9f);
      }
      pmax[j] = fmaxf(fmaxf(sc[0][j], sc[1][j]), fmaxf(sc[2][j], sc[3][j]));
    }
#pragma unroll
    for (int j = 0; j < 4; ++j)
#pragma unroll
      for (int off = 1; off < 16; off <<= 1)
        pmax[j] = fmaxf(pmax[j], __shfl_xor(pmax[j], off, 64));
    float alpha[4], rsum[4];
#pragma unroll
    for (int j = 0; j < 4; ++j) {
      float mn = fmaxf(m_r[j], pmax[j]);
      alpha[j] = __expf(m_r[j] - mn);
      m_r[j] = mn;
      rsum[j] = 0.f;
    }
#pragma unroll
    for (int ni = 0; ni < 4; ++ni)
#pragma unroll
      for (int j = 0; j < 4; ++j) {
        float p = __expf(sc[ni][j] - m_r[j]);
        sc[ni][j] = p;
        rsum[j] += p;
      }
#pragma unroll
    for (int j = 0; j < 4; ++j) {
#pragma unroll
      for (int off = 1; off < 16; off <<= 1)
        rsum[j] += __shfl_xor(rsum[j], off, 64);
      l_r[j] = l_r[j] * alpha[j] + rsum[j];
    }
#pragma unroll
    for (int di = 0; di < 4; ++di)
#pragma unroll
      for (int j = 0; j < 4; ++j) o[di][j] *= alpha[j];

    {  // P -> LDS (bf16, per-wave region)
      char* Pw = (char*)(Ps + w * 16 * 64);
#pragma unroll
      for (int ni = 0; ni < 4; ++ni)
#pragma unroll
        for (int j = 0; j < 4; ++j) {
          int row = lg * 4 + j, col = ni * 16 + l4;
          int off = row * 128 + ((col * 2) ^ ((row & 7) << 4));
          *reinterpret_cast<unsigned short*>(Pw + off) = f2bf(sc[ni][j]);
        }
    }
    __syncthreads();
    {  // O += P V
      const char* Pw = (const char*)(Ps + w * 16 * 64);
#pragma unroll
      for (int ks = 0; ks < 2; ++ks) {
        const int kb = (ks * 32 + lg * 8) * 2;
        ushort8 pa = *reinterpret_cast<const ushort8*>(Pw + l4 * 128 + (kb ^ ((l4 & 7) << 4)));
#pragma unroll
        for (int di = 0; di < 4; ++di) {
          int vr = di * 16 + l4;
          ushort8 vb = *reinterpret_cast<const ushort8*>((const char*)VTs + vr * 128 + (kb ^ ((vr & 7) << 4)));
          o[di] = mfma16(pa, vb, o[di]);
        }
      }
    }
  }

#pragma unroll
  for (int di = 0; di < 4; ++di) {
    int col = h * kDH + di * 16 + l4;
#pragma unroll
    for (int j = 0; j < 4; ++j) {
      int qrow = qt * 64 + w * 16 + lg * 4 + j;
      Og[((size_t)(b * kS + qrow)) * kD + col] = o[di][j] / l_r[j];
    }
  }
}

// ---------------------------------------------------------------------------
// out[row] = LayerNorm(x[row] + y[row]) * g + be    (D = 1024)
// ---------------------------------------------------------------------------
__global__ __launch_bounds__(256) void addln_kernel(
    const float* __restrict__ x, const float* __restrict__ y,
    const float* __restrict__ g, const float* __restrict__ be,
    float* __restrict__ out)
{
  const int row = blockIdx.x, t = threadIdx.x;
  const size_t base = (size_t)row * 1024 + t * 4;
  float4 xv = *reinterpret_cast<const float4*>(x + base);
  float4 yv = *reinterpret_cast<const float4*>(y + base);
  float v0 = xv.x + yv.x, v1 = xv.y + yv.y, v2 = xv.z + yv.z, v3 = xv.w + yv.w;
  float s1 = v0 + v1 + v2 + v3;
  float s2 = v0 * v0 + v1 * v1 + v2 * v2 + v3 * v3;
#pragma unroll
  for (int off = 1; off < 64; off <<= 1) {
    s1 += __shfl_xor(s1, off, 64);
    s2 += __shfl_xor(s2, off, 64);
  }
  __shared__ float r1[4], r2[4];
  const int w = t >> 6, lane = t & 63;
  if (lane == 0) { r1[w] = s1; r2[w] = s2; }
  __syncthreads();
  s1 = r1[0] + r1[1] + r1[2] + r1[3];
  s2 = r2[0] + r2[1] + r2[2] + r2[3];
  const float mean = s1 * (1.0f / 1024.0f);
  const float var = s2 * (1.0f / 1024.0f) - mean * mean;
  const float rs = rsqrtf(var + 1e-5f);
  float4 gv = *reinterpret_cast<const float4*>(g + t * 4);
  float4 bv = *reinterpret_cast<const float4*>(be + t * 4);
  float4 ov;
  ov.x = (v0 - mean) * rs * gv.x + bv.x;
  ov.y = (v1 - mean) * rs * gv.y + bv.y;
  ov.z = (v2 - mean) * rs * gv.z + bv.z;
  ov.w = (v3 - mean) * rs * gv.w + bv.w;
  *reinterpret_cast<float4*>(out + base) = ov;
}

// ---------------------------------------------------------------------------
extern "C" void kernel_launch(void* const* d_in, const int* in_sizes, int n_in,
                              void* d_out, int out_size, void* d_ws, size_t ws_size,
                              hipStream_t stream)
{
  const float* tgt  = (const float*)d_in[0];
  const float* memi = (const float*)d_in[1];
  const int*   mask = (const int*)d_in[2];
  const float* sa_wq = (const float*)d_in[3];  const float* sa_bq = (const float*)d_in[4];
  const float* sa_wk = (const float*)d_in[5];  const float* sa_bk = (const float*)d_in[6];
  const float* sa_wv = (const float*)d_in[7];  const float* sa_bv = (const float*)d_in[8];
  const float* sa_wo = (const float*)d_in[9];  const float* sa_bo = (const float*)d_in[10];
  const float* ca_wq = (const float*)d_in[11]; const float* ca_bq = (const float*)d_in[12];
  const float* ca_wk = (const float*)d_in[13]; const float* ca_bk = (const float*)d_in[14];
  const float* ca_wv = (const float*)d_in[15]; const float* ca_bv = (const float*)d_in[16];
  const float* ca_wo = (const float*)d_in[17]; const float* ca_bo = (const float*)d_in[18];
  const float* w1 = (const float*)d_in[19]; const float* b1 = (const float*)d_in[20];
  const float* w2 = (const float*)d_in[21]; const float* b2 = (const float*)d_in[22];
  const float* g1 = (const float*)d_in[23]; const float* be1 = (const float*)d_in[24];
  const float* g2 = (const float*)d_in[25]; const float* be2 = (const float*)d_in[26];
  const float* g3 = (const float*)d_in[27]; const float* be3 = (const float*)d_in[28];
  float* out = (float*)d_out;
  float* ws = (float*)d_ws;

  const int M = 4096;  // B*S
  // workspace layout (floats): Q/P | [H (16.7M floats) overlapping K|V|AO] | T1 | T2
  float* Qb = ws;                    // 4,194,304 floats (also P)
  float* Kb = ws + 4194304;
  float* Vb = ws + 8388608;
  float* AO = ws + 12582912;
  float* Hb = ws + 4194304;          // FFN hidden, overlaps K/V/AO (dead by then)
  float* T1 = ws + 20971520;
  float* T2 = ws + 25165824;
  float* Pb = Qb;

  dim3 blk(256);
  auto gemm = [&](const float* Aa, const float* Bww, const float* bias, float* Cc,
                  int Mm, int Nn, int Kk, int relu) {
    dim3 grid(Nn / 128, Mm / 128);
    gemm_bias_kernel<<<grid, blk, 0, stream>>>(Aa, Bww, bias, Cc, Mm, Nn, Kk, relu);
  };

  // ---- self-attention ----
  gemm(tgt, sa_wq, sa_bq, Qb, M, 1024, 1024, 0);
  gemm(tgt, sa_wk, sa_bk, Kb, M, 1024, 1024, 0);
  gemm(tgt, sa_wv, sa_bv, Vb, M, 1024, 1024, 0);
  attn_kernel<<<dim3(16, 16, 4), blk, 0, stream>>>(Qb, Kb, Vb, mask, AO);
  gemm(AO, sa_wo, sa_bo, Pb, M, 1024, 1024, 0);
  addln_kernel<<<dim3(M), blk, 0, stream>>>(tgt, Pb, g1, be1, T1);

  // ---- cross-attention ----
  gemm(T1, ca_wq, ca_bq, Qb, M, 1024, 1024, 0);
  gemm(memi, ca_wk, ca_bk, Kb, M, 1024, 1024, 0);
  gemm(memi, ca_wv, ca_bv, Vb, M, 1024, 1024, 0);
  attn_kernel<<<dim3(16, 16, 4), blk, 0, stream>>>(Qb, Kb, Vb, mask, AO);
  gemm(AO, ca_wo, ca_bo, Pb, M, 1024, 1024, 0);
  addln_kernel<<<dim3(M), blk, 0, stream>>>(T1, Pb, g2, be2, T2);

  // ---- FFN ----
  gemm(T2, w1, b1, Hb, M, 4096, 1024, 1);   // relu
  gemm(Hb, w2, b2, Pb, M, 1024, 4096, 0);
  addln_kernel<<<dim3(M), blk, 0, stream>>>(T2, Pb, g3, be3, out);

  (void)in_sizes; (void)n_in; (void)out_size; (void)ws_size;
}

// Round 2
// 510.061 us; speedup vs baseline: 1.2578x; 1.2578x over previous
//
#include <hip/hip_runtime.h>
#include <math.h>

typedef float f32x4 __attribute__((ext_vector_type(4)));
typedef unsigned short ushort8 __attribute__((ext_vector_type(8)));
typedef unsigned short ushort4v __attribute__((ext_vector_type(4)));
typedef __bf16 bf16x8 __attribute__((ext_vector_type(8)));
typedef unsigned int u32;

__device__ __forceinline__ unsigned short f2bf(float x) {
  union { float f; unsigned u; } v; v.f = x;
  unsigned r = v.u + 0x7FFFu + ((v.u >> 16) & 1u);   // RNE
  return (unsigned short)(r >> 16);
}

__device__ __forceinline__ f32x4 mfma16(ushort8 a, ushort8 b, f32x4 c) {
  return __builtin_amdgcn_mfma_f32_16x16x32_bf16(
      __builtin_bit_cast(bf16x8, a), __builtin_bit_cast(bf16x8, b), c, 0, 0, 0);
}

// async global->LDS, 16B per lane; LDS dest = wave-uniform base + lane*16
__device__ __forceinline__ void gload16(const void* g, void* l) {
  __builtin_amdgcn_global_load_lds((const __attribute__((address_space(1))) u32*)g,
                                   (__attribute__((address_space(3))) u32*)l, 16, 0, 0);
}

// ---------------------------------------------------------------------------
// bf16 GEMM: C[M,N] = A[M,K] @ Bt[N,K]^T + bias, m97 structure.
// 128x128 tile, BK=64, 4 waves (2x2). global_load_lds staging, both-sides
// swizzle: linear LDS dest, source k-slot (l&7)^(l>>3), read slot ^ (r&7).
// flags: 1 = relu, 2 = bf16 output
// ---------------------------------------------------------------------------
__global__ __launch_bounds__(256) void gemm_bf16_kernel(
    const unsigned short* __restrict__ A, const unsigned short* __restrict__ Bt,
    const float* __restrict__ bias, void* __restrict__ C,
    int M, int N, int K, int flags)
{
  __shared__ __align__(16) char As[128 * 128];  // [r][64k] bf16, swizzled slots
  __shared__ __align__(16) char Bs[128 * 128];
  const int bn = blockIdx.x, bm = blockIdx.y;
  const int t = threadIdx.x;
  const int lane = t & 63, w = t >> 6, wm = w >> 1, wn = w & 1;
  const int l4 = lane & 15, lg = lane >> 4;
  const size_t K2 = (size_t)K * 2;

  f32x4 acc[4][4];
#pragma unroll
  for (int i = 0; i < 4; ++i)
#pragma unroll
    for (int j = 0; j < 4; ++j) acc[i][j] = f32x4{0.f, 0.f, 0.f, 0.f};

  // staging per-lane source: row = w*32 + i*8 + (lane>>3), k-slot = (lane&7)^(lane>>3)
  const int lr = lane >> 3;
  const int ls = (lane & 7) ^ lr;
  const char* Ag = (const char*)A + (size_t)(bm * 128 + w * 32 + lr) * K2 + ls * 16;
  const char* Bg = (const char*)Bt + (size_t)(bn * 128 + w * 32 + lr) * K2 + ls * 16;
  char* Alb = As + w * 4096;   // wave-uniform LDS bases (chunks of 1KB)
  char* Blb = Bs + w * 4096;

  const int nkt = K >> 6;
  for (int kt = 0; kt < nkt; ++kt) {
    __syncthreads();
    const size_t ko = (size_t)kt * 128;
#pragma unroll
    for (int i = 0; i < 4; ++i) {
      gload16(Ag + i * 8 * K2 + ko, Alb + i * 1024);
      gload16(Bg + i * 8 * K2 + ko, Blb + i * 1024);
    }
    __syncthreads();   // compiler drains vmcnt before barrier
#pragma unroll
    for (int ks = 0; ks < 2; ++ks) {
      const int kb = ks * 64 + lg * 16;   // byte slot*16
      ushort8 af[4], bfr[4];
#pragma unroll
      for (int mi = 0; mi < 4; ++mi) {
        int r = wm * 64 + mi * 16 + l4;
        af[mi] = *reinterpret_cast<const ushort8*>(As + r * 128 + (kb ^ ((r & 7) << 4)));
      }
#pragma unroll
      for (int ni = 0; ni < 4; ++ni) {
        int r = wn * 64 + ni * 16 + l4;
        bfr[ni] = *reinterpret_cast<const ushort8*>(Bs + r * 128 + (kb ^ ((r & 7) << 4)));
      }
#pragma unroll
      for (int mi = 0; mi < 4; ++mi)
#pragma unroll
        for (int ni = 0; ni < 4; ++ni)
          acc[mi][ni] = mfma16(af[mi], bfr[ni], acc[mi][ni]);
    }
  }
  // epilogue: C row=(lane>>4)*4+j, col=lane&15
  const int relu = flags & 1, obf = flags & 2;
#pragma unroll
  for (int mi = 0; mi < 4; ++mi)
#pragma unroll
    for (int ni = 0; ni < 4; ++ni) {
      int col = bn * 128 + wn * 64 + ni * 16 + l4;
      float bia = bias[col];
#pragma unroll
      for (int j = 0; j < 4; ++j) {
        int row = bm * 128 + wm * 64 + mi * 16 + lg * 4 + j;
        float vv = acc[mi][ni][j] + bia;
        if (relu) vv = fmaxf(vv, 0.f);
        if (obf) ((unsigned short*)C)[(size_t)row * N + col] = f2bf(vv);
        else     ((float*)C)[(size_t)row * N + col] = vv;
      }
    }
}

// ---------------------------------------------------------------------------
// Flash attention, bf16 in/out. Q rows stride qs, K/V rows stride ks_.
// Block = (qt, h, b): 64 q-rows, 4 waves x 16 q-rows. Online softmax f32.
// ---------------------------------------------------------------------------
constexpr int kS = 1024, kD = 1024, kDH = 64;

__global__ __launch_bounds__(256) void attn_kernel(
    const unsigned short* __restrict__ Qg, const unsigned short* __restrict__ Kg,
    const unsigned short* __restrict__ Vg, int qs, int ks_,
    const int* __restrict__ maskg, unsigned short* __restrict__ Og)
{
  __shared__ __align__(16) char Qs[64 * 128];   // [q][64d] bf16
  __shared__ __align__(16) char Ks[64 * 128];   // [key][64d]
  __shared__ __align__(16) char VTs[64 * 128];  // [d][64key]
  __shared__ __align__(16) char Ps[4 * 16 * 128];  // per-wave [q16][key64]
  const int qt = blockIdx.x, h = blockIdx.y, b = blockIdx.z;
  const int t = threadIdx.x, lane = t & 63, w = t >> 6;
  const int l4 = lane & 15, lg = lane >> 4;

  {  // stage Q once
    int r = t >> 2, c0 = (t & 3) * 16;
    const unsigned short* src = Qg + (size_t)(b * kS + qt * 64 + r) * qs + h * kDH + c0;
#pragma unroll
    for (int hf = 0; hf < 2; ++hf) {
      ushort8 v = *reinterpret_cast<const ushort8*>(src + hf * 8);
      int c = c0 + hf * 8;
      *reinterpret_cast<ushort8*>(Qs + r * 128 + ((c * 2) ^ ((r & 7) << 4))) = v;
    }
  }

  float m_r[4], l_r[4];
  f32x4 o[4];
#pragma unroll
  for (int j = 0; j < 4; ++j) { m_r[j] = -1e30f; l_r[j] = 0.f; }
#pragma unroll
  for (int di = 0; di < 4; ++di) o[di] = f32x4{0.f, 0.f, 0.f, 0.f};

  for (int kt = 0; kt < kS / 64; ++kt) {
    __syncthreads();
    {  // stage K tile
      int r = t >> 2, c0 = (t & 3) * 16;
      const unsigned short* src = Kg + (size_t)(b * kS + kt * 64 + r) * ks_ + h * kDH + c0;
#pragma unroll
      for (int hf = 0; hf < 2; ++hf) {
        ushort8 v = *reinterpret_cast<const ushort8*>(src + hf * 8);
        int c = c0 + hf * 8;
        *reinterpret_cast<ushort8*>(Ks + r * 128 + ((c * 2) ^ ((r & 7) << 4))) = v;
      }
    }
    {  // stage V transposed [d][key]
      int key = t >> 2, c0 = (t & 3) * 16;
      const unsigned short* src = Vg + (size_t)(b * kS + kt * 64 + key) * ks_ + h * kDH + c0;
      ushort8 v0 = *reinterpret_cast<const ushort8*>(src);
      ushort8 v1 = *reinterpret_cast<const ushort8*>(src + 8);
#pragma unroll
      for (int i = 0; i < 16; ++i) {
        int dh = c0 + i;
        unsigned short vv = (i < 8) ? v0[i] : v1[i - 8];
        *reinterpret_cast<unsigned short*>(VTs + dh * 128 + ((key * 2) ^ ((dh & 7) << 4))) = vv;
      }
    }
    __syncthreads();

    // S = Q K^T (wave's 16 q-rows x 64 keys)
    f32x4 sc[4];
#pragma unroll
    for (int ni = 0; ni < 4; ++ni) sc[ni] = f32x4{0.f, 0.f, 0.f, 0.f};
#pragma unroll
    for (int ks = 0; ks < 2; ++ks) {
      const int kb = ks * 64 + lg * 16;
      int qr = w * 16 + l4;
      ushort8 a = *reinterpret_cast<const ushort8*>(Qs + qr * 128 + (kb ^ ((qr & 7) << 4)));
#pragma unroll
      for (int ni = 0; ni < 4; ++ni) {
        int kr = ni * 16 + l4;
        ushort8 bb = *reinterpret_cast<const ushort8*>(Ks + kr * 128 + (kb ^ ((kr & 7) << 4)));
        sc[ni] = mfma16(a, bb, sc[ni]);
      }
    }

    // scale + mask + online softmax (C layout: row=lg*4+j (q), col=ni*16+l4 (key))
    const int qbase = qt * 64 + w * 16;
    float pmax[4];
#pragma unroll
    for (int j = 0; j < 4; ++j) {
      int qrow = qbase + lg * 4 + j;
      const int* mrow = maskg + ((size_t)b * kS + qrow) * kS + kt * 64;
#pragma unroll
      for (int ni = 0; ni < 4; ++ni) {
        float mv = (float)mrow[ni * 16 + l4];
        sc[ni][j] = sc[ni][j] * 0.125f + (1.0f - mv) * (-1e9f);
      }
      pmax[j] = fmaxf(fmaxf(sc[0][j], sc[1][j]), fmaxf(sc[2][j], sc[3][j]));
    }
#pragma unroll
    for (int j = 0; j < 4; ++j)
#pragma unroll
      for (int off = 1; off < 16; off <<= 1)
        pmax[j] = fmaxf(pmax[j], __shfl_xor(pmax[j], off, 64));
    float alpha[4], rsum[4];
#pragma unroll
    for (int j = 0; j < 4; ++j) {
      float mn = fmaxf(m_r[j], pmax[j]);
      alpha[j] = __expf(m_r[j] - mn);
      m_r[j] = mn;
      rsum[j] = 0.f;
    }
#pragma unroll
    for (int ni = 0; ni < 4; ++ni)
#pragma unroll
      for (int j = 0; j < 4; ++j) {
        float p = __expf(sc[ni][j] - m_r[j]);
        sc[ni][j] = p;
        rsum[j] += p;
      }
#pragma unroll
    for (int j = 0; j < 4; ++j) {
#pragma unroll
      for (int off = 1; off < 16; off <<= 1)
        rsum[j] += __shfl_xor(rsum[j], off, 64);
      l_r[j] = l_r[j] * alpha[j] + rsum[j];
    }
#pragma unroll
    for (int di = 0; di < 4; ++di)
#pragma unroll
      for (int j = 0; j < 4; ++j) o[di][j] *= alpha[j];

    {  // P -> LDS (bf16, per-wave region)
      char* Pw = Ps + w * 2048;
#pragma unroll
      for (int ni = 0; ni < 4; ++ni)
#pragma unroll
        for (int j = 0; j < 4; ++j) {
          int row = lg * 4 + j, col = ni * 16 + l4;
          *reinterpret_cast<unsigned short*>(Pw + row * 128 + ((col * 2) ^ ((row & 7) << 4))) = f2bf(sc[ni][j]);
        }
    }
    __syncthreads();
    {  // O += P V
      const char* Pw = Ps + w * 2048;
#pragma unroll
      for (int ks = 0; ks < 2; ++ks) {
        const int kb = ks * 64 + lg * 16;
        ushort8 pa = *reinterpret_cast<const ushort8*>(Pw + l4 * 128 + (kb ^ ((l4 & 7) << 4)));
#pragma unroll
        for (int di = 0; di < 4; ++di) {
          int vr = di * 16 + l4;
          ushort8 vb = *reinterpret_cast<const ushort8*>(VTs + vr * 128 + (kb ^ ((vr & 7) << 4)));
          o[di] = mfma16(pa, vb, o[di]);
        }
      }
    }
  }

#pragma unroll
  for (int di = 0; di < 4; ++di) {
    int col = h * kDH + di * 16 + l4;
#pragma unroll
    for (int j = 0; j < 4; ++j) {
      int qrow = qt * 64 + w * 16 + lg * 4 + j;
      Og[(size_t)(b * kS + qrow) * kD + col] = f2bf(o[di][j] / l_r[j]);
    }
  }
}

// ---------------------------------------------------------------------------
// out = LayerNorm(x + y) * g + be (D=1024), f32 out + optional bf16 copy
// ---------------------------------------------------------------------------
__global__ __launch_bounds__(256) void addln_kernel(
    const float* __restrict__ x, const float* __restrict__ y,
    const float* __restrict__ g, const float* __restrict__ be,
    float* __restrict__ out, unsigned short* __restrict__ ob)
{
  const int row = blockIdx.x, t = threadIdx.x;
  const size_t base = (size_t)row * 1024 + t * 4;
  float4 xv = *reinterpret_cast<const float4*>(x + base);
  float4 yv = *reinterpret_cast<const float4*>(y + base);
  float v0 = xv.x + yv.x, v1 = xv.y + yv.y, v2 = xv.z + yv.z, v3 = xv.w + yv.w;
  float s1 = v0 + v1 + v2 + v3;
  float s2 = v0 * v0 + v1 * v1 + v2 * v2 + v3 * v3;
#pragma unroll
  for (int off = 1; off < 64; off <<= 1) {
    s1 += __shfl_xor(s1, off, 64);
    s2 += __shfl_xor(s2, off, 64);
  }
  __shared__ float r1[4], r2[4];
  const int w = t >> 6, lane = t & 63;
  if (lane == 0) { r1[w] = s1; r2[w] = s2; }
  __syncthreads();
  s1 = r1[0] + r1[1] + r1[2] + r1[3];
  s2 = r2[0] + r2[1] + r2[2] + r2[3];
  const float mean = s1 * (1.0f / 1024.0f);
  const float var = s2 * (1.0f / 1024.0f) - mean * mean;
  const float rs = rsqrtf(var + 1e-5f);
  float4 gv = *reinterpret_cast<const float4*>(g + t * 4);
  float4 bv = *reinterpret_cast<const float4*>(be + t * 4);
  float4 ov;
  ov.x = (v0 - mean) * rs * gv.x + bv.x;
  ov.y = (v1 - mean) * rs * gv.y + bv.y;
  ov.z = (v2 - mean) * rs * gv.z + bv.z;
  ov.w = (v3 - mean) * rs * gv.w + bv.w;
  *reinterpret_cast<float4*>(out + base) = ov;
  if (ob) {
    ushort4v bo;
    bo[0] = f2bf(ov.x); bo[1] = f2bf(ov.y); bo[2] = f2bf(ov.z); bo[3] = f2bf(ov.w);
    *reinterpret_cast<ushort4v*>(ob + base) = bo;
  }
}

// ---------------------------------------------------------------------------
// f32 -> bf16 convert (8 elems/thread)
// ---------------------------------------------------------------------------
__global__ __launch_bounds__(256) void cvt_bf16_kernel(
    const float* __restrict__ src, unsigned short* __restrict__ dst, int n8)
{
  int i = blockIdx.x * 256 + threadIdx.x;
  if (i >= n8) return;
  float4 f0 = reinterpret_cast<const float4*>(src)[i * 2];
  float4 f1 = reinterpret_cast<const float4*>(src)[i * 2 + 1];
  ushort8 v;
  v[0] = f2bf(f0.x); v[1] = f2bf(f0.y); v[2] = f2bf(f0.z); v[3] = f2bf(f0.w);
  v[4] = f2bf(f1.x); v[5] = f2bf(f1.y); v[6] = f2bf(f1.z); v[7] = f2bf(f1.w);
  reinterpret_cast<ushort8*>(dst)[i] = v;
}

// ---------------------------------------------------------------------------
// W[K][N] f32 -> Wt[n][k] bf16 (dst stride = K), 32x32 LDS tile
// ---------------------------------------------------------------------------
__global__ __launch_bounds__(256) void transpose_cvt_kernel(
    const float* __restrict__ src, unsigned short* __restrict__ dst, int K, int N)
{
  __shared__ float tile[32][33];
  const int bx = blockIdx.x, by = blockIdx.y;   // bx: n-tile, by: k-tile
  const int tx = threadIdx.x & 31, ty = threadIdx.x >> 5;
#pragma unroll
  for (int i = 0; i < 4; ++i)
    tile[ty + i * 8][tx] = src[(size_t)(by * 32 + ty + i * 8) * N + bx * 32 + tx];
  __syncthreads();
#pragma unroll
  for (int i = 0; i < 4; ++i)
    dst[(size_t)(bx * 32 + ty + i * 8) * K + by * 32 + tx] = f2bf(tile[tx][ty + i * 8]);
}

__global__ void concat_bias_kernel(const float* a, const float* b, const float* c,
                                   float* dst, int n) {
  int i = blockIdx.x * 256 + threadIdx.x;
  if (i >= n) return;
  dst[i] = (i < 1024) ? a[i] : (i < 2048 ? b[i - 1024] : c[i - 2048]);
}

// ---------------------------------------------------------------------------
extern "C" void kernel_launch(void* const* d_in, const int* in_sizes, int n_in,
                              void* d_out, int out_size, void* d_ws, size_t ws_size,
                              hipStream_t stream)
{
  const float* tgt  = (const float*)d_in[0];
  const float* memi = (const float*)d_in[1];
  const int*   mask = (const int*)d_in[2];
  const float* sa_wq = (const float*)d_in[3];  const float* sa_bq = (const float*)d_in[4];
  const float* sa_wk = (const float*)d_in[5];  const float* sa_bk = (const float*)d_in[6];
  const float* sa_wv = (const float*)d_in[7];  const float* sa_bv = (const float*)d_in[8];
  const float* sa_wo = (const float*)d_in[9];  const float* sa_bo = (const float*)d_in[10];
  const float* ca_wq = (const float*)d_in[11]; const float* ca_bq = (const float*)d_in[12];
  const float* ca_wk = (const float*)d_in[13]; const float* ca_bk = (const float*)d_in[14];
  const float* ca_wv = (const float*)d_in[15]; const float* ca_bv = (const float*)d_in[16];
  const float* ca_wo = (const float*)d_in[17]; const float* ca_bo = (const float*)d_in[18];
  const float* w1 = (const float*)d_in[19]; const float* b1 = (const float*)d_in[20];
  const float* w2 = (const float*)d_in[21]; const float* b2 = (const float*)d_in[22];
  const float* g1 = (const float*)d_in[23]; const float* be1 = (const float*)d_in[24];
  const float* g2 = (const float*)d_in[25]; const float* be2 = (const float*)d_in[26];
  const float* g3 = (const float*)d_in[27]; const float* be3 = (const float*)d_in[28];
  float* out = (float*)d_out;
  char* W = (char*)d_ws;
  const size_t MB = 1 << 20;
  typedef unsigned short us;

  // workspace layout (byte offsets, total 113 MB; stream order makes reuses safe)
  us* Wsaqkv = (us*)(W + 0);          // [3072][1024] bf16
  us* Wsao   = (us*)(W + 6 * MB);     // [1024][1024]
  us* Wcaq   = (us*)(W + 8 * MB);
  us* Wcakv  = (us*)(W + 10 * MB);    // [2048][1024]
  us* Wcao   = (us*)(W + 14 * MB);
  us* W1t    = (us*)(W + 16 * MB);    // [4096][1024]
  us* W2t    = (us*)(W + 24 * MB);    // [1024][4096]
  float* b_saqkv = (float*)(W + 32 * MB);            // 3072 f32
  float* b_cakv  = (float*)(W + 32 * MB + 16384);    // 2048 f32
  us* tgt_bf = (us*)(W + 33 * MB);    // 8MB; dead after SA-QKV gemm -> reused as T2b
  us* T2b    = tgt_bf;
  us* mem_bf = (us*)(W + 41 * MB);    // 8MB; dead after CA-KV gemm
  us* QKV    = (us*)(W + 49 * MB);    // SA: [4096][3072] bf16, 24MB
  us* Qca    = (us*)(W + 49 * MB);    // CA: [4096][1024], 8MB
  us* KVca   = (us*)(W + 57 * MB);    // CA: [4096][2048], 16MB (overwrites T1b after CA-Q)
  us* T1b    = (us*)(W + 65 * MB);    // 8MB
  us* AO     = (us*)(W + 73 * MB);    // [4096][1024] bf16, 8MB
  us* Hb     = (us*)(W + 49 * MB);    // FFN hidden [4096][4096] bf16, 32MB (QKV/AO dead)
  float* Op  = (float*)(W + 81 * MB); // [4096][1024] f32, 16MB; also FFN2 out
  float* T1f = (float*)(W + 97 * MB); // 16MB; T2f aliases (in-place addln)
  float* T2f = T1f;

  const int M = 4096;
  dim3 blk(256);
  auto gemm = [&](const us* Aa, const us* Bta, const float* bias, void* Cc,
                  int Nn, int Kk, int flags) {
    gemm_bf16_kernel<<<dim3(Nn / 128, M / 128), blk, 0, stream>>>(Aa, Bta, bias, Cc, M, Nn, Kk, flags);
  };
  auto tcvt = [&](const float* s, us* d, int Kk, int Nn) {
    transpose_cvt_kernel<<<dim3(Nn / 32, Kk / 32), blk, 0, stream>>>(s, d, Kk, Nn);
  };

  // ---- conversions ----
  tcvt(sa_wq, Wsaqkv, 1024, 1024);
  tcvt(sa_wk, Wsaqkv + 1024 * 1024, 1024, 1024);
  tcvt(sa_wv, Wsaqkv + 2048 * 1024, 1024, 1024);
  tcvt(sa_wo, Wsao, 1024, 1024);
  tcvt(ca_wq, Wcaq, 1024, 1024);
  tcvt(ca_wk, Wcakv, 1024, 1024);
  tcvt(ca_wv, Wcakv + 1024 * 1024, 1024, 1024);
  tcvt(ca_wo, Wcao, 1024, 1024);
  tcvt(w1, W1t, 1024, 4096);
  tcvt(w2, W2t, 4096, 1024);
  cvt_bf16_kernel<<<dim3(2048), blk, 0, stream>>>(tgt, tgt_bf, M * 1024 / 8);
  cvt_bf16_kernel<<<dim3(2048), blk, 0, stream>>>(memi, mem_bf, M * 1024 / 8);
  concat_bias_kernel<<<dim3(12), blk, 0, stream>>>(sa_bq, sa_bk, sa_bv, b_saqkv, 3072);
  concat_bias_kernel<<<dim3(8), blk, 0, stream>>>(ca_bk, ca_bv, ca_bv, b_cakv, 2048);

  // ---- self-attention ----
  gemm(tgt_bf, Wsaqkv, b_saqkv, QKV, 3072, 1024, 2);
  attn_kernel<<<dim3(16, 16, 4), blk, 0, stream>>>(QKV, QKV + 1024, QKV + 2048, 3072, 3072, mask, AO);
  gemm(AO, Wsao, sa_bo, Op, 1024, 1024, 0);
  addln_kernel<<<dim3(M), blk, 0, stream>>>(tgt, Op, g1, be1, T1f, T1b);

  // ---- cross-attention ----
  gemm(T1b, Wcaq, ca_bq, Qca, 1024, 1024, 2);
  gemm(mem_bf, Wcakv, b_cakv, KVca, 2048, 1024, 2);
  attn_kernel<<<dim3(16, 16, 4), blk, 0, stream>>>(Qca, KVca, KVca + 1024, 1024, 2048, mask, AO);
  gemm(AO, Wcao, ca_bo, Op, 1024, 1024, 0);
  addln_kernel<<<dim3(M), blk, 0, stream>>>(T1f, Op, g2, be2, T2f, T2b);

  // ---- FFN ----
  gemm(T2b, W1t, b1, Hb, 4096, 1024, 3);        // relu + bf16 out
  gemm(Hb, W2t, b2, Op, 1024, 4096, 0);
  addln_kernel<<<dim3(M), blk, 0, stream>>>(T2f, Op, g3, be3, out, nullptr);

  (void)in_sizes; (void)n_in; (void)out_size; (void)ws_size; (void)mask;
}

// Round 3
// 445.863 us; speedup vs baseline: 1.4389x; 1.1440x over previous
//
#include <hip/hip_runtime.h>
#include <math.h>

typedef float f32x4 __attribute__((ext_vector_type(4)));
typedef unsigned short ushort8 __attribute__((ext_vector_type(8)));
typedef unsigned short ushort4v __attribute__((ext_vector_type(4)));
typedef __bf16 bf16x8 __attribute__((ext_vector_type(8)));
typedef unsigned int u32;

__device__ __forceinline__ unsigned short f2bf(float x) {
  union { float f; unsigned u; } v; v.f = x;
  unsigned r = v.u + 0x7FFFu + ((v.u >> 16) & 1u);   // RNE
  return (unsigned short)(r >> 16);
}

__device__ __forceinline__ f32x4 mfma16(ushort8 a, ushort8 b, f32x4 c) {
  return __builtin_amdgcn_mfma_f32_16x16x32_bf16(
      __builtin_bit_cast(bf16x8, a), __builtin_bit_cast(bf16x8, b), c, 0, 0, 0);
}

// async global->LDS, 16B per lane; LDS dest = wave-uniform base + lane*16
__device__ __forceinline__ void gload16(const void* g, void* l) {
  __builtin_amdgcn_global_load_lds((const __attribute__((address_space(1))) u32*)g,
                                   (__attribute__((address_space(3))) u32*)l, 16, 0, 0);
}

// ---------------------------------------------------------------------------
// bf16 GEMM: C[M,N] = A[M,K] @ Bt[N,K]^T + bias.
// 128x128 tile, BK=64, 4 waves (2x2). Double-buffered 2-phase pipeline:
// STAGE(next buffer) issued BEFORE compute(cur); __syncthreads() at phase end
// is the {vmcnt(0); barrier} drain. Distinct __shared__ arrays per buffer so
// AA proves gload_lds writes don't alias current ds_reads.
// flags: 1 = relu, 2 = bf16 output
// ---------------------------------------------------------------------------
__global__ __launch_bounds__(256) void gemm_bf16_kernel(
    const unsigned short* __restrict__ A, const unsigned short* __restrict__ Bt,
    const float* __restrict__ bias, void* __restrict__ C,
    int M, int N, int K, int flags)
{
  __shared__ __align__(16) char As0[128 * 128];
  __shared__ __align__(16) char Bs0[128 * 128];
  __shared__ __align__(16) char As1[128 * 128];
  __shared__ __align__(16) char Bs1[128 * 128];
  const int bn = blockIdx.x, bm = blockIdx.y;
  const int t = threadIdx.x;
  const int lane = t & 63, w = t >> 6, wm = w >> 1, wn = w & 1;
  const int l4 = lane & 15, lg = lane >> 4;
  const size_t K2 = (size_t)K * 2;

  f32x4 acc[4][4];
#pragma unroll
  for (int i = 0; i < 4; ++i)
#pragma unroll
    for (int j = 0; j < 4; ++j) acc[i][j] = f32x4{0.f, 0.f, 0.f, 0.f};

  // staging: row = w*32 + i*8 + (lane>>3), k-slot = (lane&7)^(lane>>3) (inverse swizzle)
  const int lr = lane >> 3;
  const int ls = (lane & 7) ^ lr;
  const char* Ag = (const char*)A + (size_t)(bm * 128 + w * 32 + lr) * K2 + ls * 16;
  const char* Bg = (const char*)Bt + (size_t)(bn * 128 + w * 32 + lr) * K2 + ls * 16;
  const int wo = w * 4096;

  auto STAGE = [&](char* Al, char* Bl, int kt) {
    const size_t ko = (size_t)kt * 128;
#pragma unroll
    for (int i = 0; i < 4; ++i) {
      gload16(Ag + i * 8 * K2 + ko, Al + wo + i * 1024);
      gload16(Bg + i * 8 * K2 + ko, Bl + wo + i * 1024);
    }
  };
  auto COMPUTE = [&](const char* As, const char* Bs) {
#pragma unroll
    for (int ks = 0; ks < 2; ++ks) {
      const int kb = ks * 64 + lg * 16;
      ushort8 af[4], bfr[4];
#pragma unroll
      for (int mi = 0; mi < 4; ++mi) {
        int r = wm * 64 + mi * 16 + l4;
        af[mi] = *reinterpret_cast<const ushort8*>(As + r * 128 + (kb ^ ((r & 7) << 4)));
      }
#pragma unroll
      for (int ni = 0; ni < 4; ++ni) {
        int r = wn * 64 + ni * 16 + l4;
        bfr[ni] = *reinterpret_cast<const ushort8*>(Bs + r * 128 + (kb ^ ((r & 7) << 4)));
      }
#pragma unroll
      for (int mi = 0; mi < 4; ++mi)
#pragma unroll
        for (int ni = 0; ni < 4; ++ni)
          acc[mi][ni] = mfma16(af[mi], bfr[ni], acc[mi][ni]);
    }
  };

  const int nkt = K >> 6;   // always even here (16 or 64)
  STAGE(As0, Bs0, 0);
  __syncthreads();          // drain prologue loads
  for (int kt = 0; kt < nkt; kt += 2) {
    STAGE(As1, Bs1, kt + 1);          // overlaps compute below
    COMPUTE(As0, Bs0);
    __syncthreads();                  // vmcnt(0) + barrier
    if (kt + 2 < nkt) STAGE(As0, Bs0, kt + 2);
    COMPUTE(As1, Bs1);
    __syncthreads();
  }

  // epilogue: C row=(lane>>4)*4+j, col=lane&15
  const int relu = flags & 1, obf = flags & 2;
#pragma unroll
  for (int mi = 0; mi < 4; ++mi)
#pragma unroll
    for (int ni = 0; ni < 4; ++ni) {
      int col = bn * 128 + wn * 64 + ni * 16 + l4;
      float bia = bias[col];
#pragma unroll
      for (int j = 0; j < 4; ++j) {
        int row = bm * 128 + wm * 64 + mi * 16 + lg * 4 + j;
        float vv = acc[mi][ni][j] + bia;
        if (relu) vv = fmaxf(vv, 0.f);
        if (obf) ((unsigned short*)C)[(size_t)row * N + col] = f2bf(vv);
        else     ((float*)C)[(size_t)row * N + col] = vv;
      }
    }
}

// ---------------------------------------------------------------------------
// Flash attention, bf16 in/out. Q rows stride qs, K/V rows stride ks_.
// Block = (qt, h, b): 64 q-rows, 4 waves x 16 q-rows. Online softmax f32.
// ---------------------------------------------------------------------------
constexpr int kS = 1024, kD = 1024, kDH = 64;

__global__ __launch_bounds__(256) void attn_kernel(
    const unsigned short* __restrict__ Qg, const unsigned short* __restrict__ Kg,
    const unsigned short* __restrict__ Vg, int qs, int ks_,
    const int* __restrict__ maskg, unsigned short* __restrict__ Og)
{
  __shared__ __align__(16) char Qs[64 * 128];   // [q][64d] bf16
  __shared__ __align__(16) char Ks[64 * 128];   // [key][64d]
  __shared__ __align__(16) char VTs[64 * 128];  // [d][64key]
  __shared__ __align__(16) char Ps[4 * 16 * 128];  // per-wave [q16][key64]
  const int qt = blockIdx.x, h = blockIdx.y, b = blockIdx.z;
  const int t = threadIdx.x, lane = t & 63, w = t >> 6;
  const int l4 = lane & 15, lg = lane >> 4;

  {  // stage Q once
    int r = t >> 2, c0 = (t & 3) * 16;
    const unsigned short* src = Qg + (size_t)(b * kS + qt * 64 + r) * qs + h * kDH + c0;
#pragma unroll
    for (int hf = 0; hf < 2; ++hf) {
      ushort8 v = *reinterpret_cast<const ushort8*>(src + hf * 8);
      int c = c0 + hf * 8;
      *reinterpret_cast<ushort8*>(Qs + r * 128 + ((c * 2) ^ ((r & 7) << 4))) = v;
    }
  }

  float m_r[4], l_r[4];
  f32x4 o[4];
#pragma unroll
  for (int j = 0; j < 4; ++j) { m_r[j] = -1e30f; l_r[j] = 0.f; }
#pragma unroll
  for (int di = 0; di < 4; ++di) o[di] = f32x4{0.f, 0.f, 0.f, 0.f};

  for (int kt = 0; kt < kS / 64; ++kt) {
    __syncthreads();
    {  // stage K tile
      int r = t >> 2, c0 = (t & 3) * 16;
      const unsigned short* src = Kg + (size_t)(b * kS + kt * 64 + r) * ks_ + h * kDH + c0;
#pragma unroll
      for (int hf = 0; hf < 2; ++hf) {
        ushort8 v = *reinterpret_cast<const ushort8*>(src + hf * 8);
        int c = c0 + hf * 8;
        *reinterpret_cast<ushort8*>(Ks + r * 128 + ((c * 2) ^ ((r & 7) << 4))) = v;
      }
    }
    {  // stage V transposed [d][key]
      int key = t >> 2, c0 = (t & 3) * 16;
      const unsigned short* src = Vg + (size_t)(b * kS + kt * 64 + key) * ks_ + h * kDH + c0;
      ushort8 v0 = *reinterpret_cast<const ushort8*>(src);
      ushort8 v1 = *reinterpret_cast<const ushort8*>(src + 8);
#pragma unroll
      for (int i = 0; i < 16; ++i) {
        int dh = c0 + i;
        unsigned short vv = (i < 8) ? v0[i] : v1[i - 8];
        *reinterpret_cast<unsigned short*>(VTs + dh * 128 + ((key * 2) ^ ((dh & 7) << 4))) = vv;
      }
    }
    __syncthreads();

    // S = Q K^T (wave's 16 q-rows x 64 keys)
    f32x4 sc[4];
#pragma unroll
    for (int ni = 0; ni < 4; ++ni) sc[ni] = f32x4{0.f, 0.f, 0.f, 0.f};
#pragma unroll
    for (int ks = 0; ks < 2; ++ks) {
      const int kb = ks * 64 + lg * 16;
      int qr = w * 16 + l4;
      ushort8 a = *reinterpret_cast<const ushort8*>(Qs + qr * 128 + (kb ^ ((qr & 7) << 4)));
#pragma unroll
      for (int ni = 0; ni < 4; ++ni) {
        int kr = ni * 16 + l4;
        ushort8 bb = *reinterpret_cast<const ushort8*>(Ks + kr * 128 + (kb ^ ((kr & 7) << 4)));
        sc[ni] = mfma16(a, bb, sc[ni]);
      }
    }

    // scale + mask + online softmax (C layout: row=lg*4+j (q), col=ni*16+l4 (key))
    const int qbase = qt * 64 + w * 16;
    float pmax[4];
#pragma unroll
    for (int j = 0; j < 4; ++j) {
      int qrow = qbase + lg * 4 + j;
      const int* mrow = maskg + ((size_t)b * kS + qrow) * kS + kt * 64;
#pragma unroll
      for (int ni = 0; ni < 4; ++ni) {
        float mv = (float)mrow[ni * 16 + l4];
        sc[ni][j] = sc[ni][j] * 0.125f + (1.0f - mv) * (-1e9f);
      }
      pmax[j] = fmaxf(fmaxf(sc[0][j], sc[1][j]), fmaxf(sc[2][j], sc[3][j]));
    }
#pragma unroll
    for (int j = 0; j < 4; ++j)
#pragma unroll
      for (int off = 1; off < 16; off <<= 1)
        pmax[j] = fmaxf(pmax[j], __shfl_xor(pmax[j], off, 64));
    float alpha[4], rsum[4];
#pragma unroll
    for (int j = 0; j < 4; ++j) {
      float mn = fmaxf(m_r[j], pmax[j]);
      alpha[j] = __expf(m_r[j] - mn);
      m_r[j] = mn;
      rsum[j] = 0.f;
    }
#pragma unroll
    for (int ni = 0; ni < 4; ++ni)
#pragma unroll
      for (int j = 0; j < 4; ++j) {
        float p = __expf(sc[ni][j] - m_r[j]);
        sc[ni][j] = p;
        rsum[j] += p;
      }
#pragma unroll
    for (int j = 0; j < 4; ++j) {
#pragma unroll
      for (int off = 1; off < 16; off <<= 1)
        rsum[j] += __shfl_xor(rsum[j], off, 64);
      l_r[j] = l_r[j] * alpha[j] + rsum[j];
    }
#pragma unroll
    for (int di = 0; di < 4; ++di)
#pragma unroll
      for (int j = 0; j < 4; ++j) o[di][j] *= alpha[j];

    {  // P -> LDS (bf16, per-wave region)
      char* Pw = Ps + w * 2048;
#pragma unroll
      for (int ni = 0; ni < 4; ++ni)
#pragma unroll
        for (int j = 0; j < 4; ++j) {
          int row = lg * 4 + j, col = ni * 16 + l4;
          *reinterpret_cast<unsigned short*>(Pw + row * 128 + ((col * 2) ^ ((row & 7) << 4))) = f2bf(sc[ni][j]);
        }
    }
    __syncthreads();
    {  // O += P V
      const char* Pw = Ps + w * 2048;
#pragma unroll
      for (int ks = 0; ks < 2; ++ks) {
        const int kb = ks * 64 + lg * 16;
        ushort8 pa = *reinterpret_cast<const ushort8*>(Pw + l4 * 128 + (kb ^ ((l4 & 7) << 4)));
#pragma unroll
        for (int di = 0; di < 4; ++di) {
          int vr = di * 16 + l4;
          ushort8 vb = *reinterpret_cast<const ushort8*>(VTs + vr * 128 + (kb ^ ((vr & 7) << 4)));
          o[di] = mfma16(pa, vb, o[di]);
        }
      }
    }
  }

#pragma unroll
  for (int di = 0; di < 4; ++di) {
    int col = h * kDH + di * 16 + l4;
#pragma unroll
    for (int j = 0; j < 4; ++j) {
      int qrow = qt * 64 + w * 16 + lg * 4 + j;
      Og[(size_t)(b * kS + qrow) * kD + col] = f2bf(o[di][j] / l_r[j]);
    }
  }
}

// ---------------------------------------------------------------------------
// out = LayerNorm(x + y) * g + be (D=1024), f32 out + optional bf16 copy
// ---------------------------------------------------------------------------
__global__ __launch_bounds__(256) void addln_kernel(
    const float* __restrict__ x, const float* __restrict__ y,
    const float* __restrict__ g, const float* __restrict__ be,
    float* __restrict__ out, unsigned short* __restrict__ ob)
{
  const int row = blockIdx.x, t = threadIdx.x;
  const size_t base = (size_t)row * 1024 + t * 4;
  float4 xv = *reinterpret_cast<const float4*>(x + base);
  float4 yv = *reinterpret_cast<const float4*>(y + base);
  float v0 = xv.x + yv.x, v1 = xv.y + yv.y, v2 = xv.z + yv.z, v3 = xv.w + yv.w;
  float s1 = v0 + v1 + v2 + v3;
  float s2 = v0 * v0 + v1 * v1 + v2 * v2 + v3 * v3;
#pragma unroll
  for (int off = 1; off < 64; off <<= 1) {
    s1 += __shfl_xor(s1, off, 64);
    s2 += __shfl_xor(s2, off, 64);
  }
  __shared__ float r1[4], r2[4];
  const int w = t >> 6, lane = t & 63;
  if (lane == 0) { r1[w] = s1; r2[w] = s2; }
  __syncthreads();
  s1 = r1[0] + r1[1] + r1[2] + r1[3];
  s2 = r2[0] + r2[1] + r2[2] + r2[3];
  const float mean = s1 * (1.0f / 1024.0f);
  const float var = s2 * (1.0f / 1024.0f) - mean * mean;
  const float rs = rsqrtf(var + 1e-5f);
  float4 gv = *reinterpret_cast<const float4*>(g + t * 4);
  float4 bv = *reinterpret_cast<const float4*>(be + t * 4);
  float4 ov;
  ov.x = (v0 - mean) * rs * gv.x + bv.x;
  ov.y = (v1 - mean) * rs * gv.y + bv.y;
  ov.z = (v2 - mean) * rs * gv.z + bv.z;
  ov.w = (v3 - mean) * rs * gv.w + bv.w;
  *reinterpret_cast<float4*>(out + base) = ov;
  if (ob) {
    ushort4v bo;
    bo[0] = f2bf(ov.x); bo[1] = f2bf(ov.y); bo[2] = f2bf(ov.z); bo[3] = f2bf(ov.w);
    *reinterpret_cast<ushort4v*>(ob + base) = bo;
  }
}

// ---------------------------------------------------------------------------
// two-tensor f32 -> bf16 convert (8 elems/thread)
// ---------------------------------------------------------------------------
__global__ __launch_bounds__(256) void cvt2_bf16_kernel(
    const float* __restrict__ a, const float* __restrict__ b,
    unsigned short* __restrict__ da, unsigned short* __restrict__ db, int n8each)
{
  int i = blockIdx.x * 256 + threadIdx.x;
  const float* s = a; unsigned short* d = da;
  if (i >= n8each) { s = b; d = db; i -= n8each; }
  if (i >= n8each) return;
  float4 f0 = reinterpret_cast<const float4*>(s)[i * 2];
  float4 f1 = reinterpret_cast<const float4*>(s)[i * 2 + 1];
  ushort8 v;
  v[0] = f2bf(f0.x); v[1] = f2bf(f0.y); v[2] = f2bf(f0.z); v[3] = f2bf(f0.w);
  v[4] = f2bf(f1.x); v[5] = f2bf(f1.y); v[6] = f2bf(f1.z); v[7] = f2bf(f1.w);
  reinterpret_cast<ushort8*>(d)[i] = v;
}

// ---------------------------------------------------------------------------
// W[K][N] f32 -> Wt[n][k] bf16 (dst stride = K), 32x32 LDS tile
// ---------------------------------------------------------------------------
__global__ __launch_bounds__(256) void transpose_cvt_kernel(
    const float* __restrict__ src, unsigned short* __restrict__ dst, int K, int N)
{
  __shared__ float tile[32][33];
  const int bx = blockIdx.x, by = blockIdx.y;   // bx: n-tile, by: k-tile
  const int tx = threadIdx.x & 31, ty = threadIdx.x >> 5;
#pragma unroll
  for (int i = 0; i < 4; ++i)
    tile[ty + i * 8][tx] = src[(size_t)(by * 32 + ty + i * 8) * N + bx * 32 + tx];
  __syncthreads();
#pragma unroll
  for (int i = 0; i < 4; ++i)
    dst[(size_t)(bx * 32 + ty + i * 8) * K + by * 32 + tx] = f2bf(tile[tx][ty + i * 8]);
}

// batched 1024x1024 transposes (8 weights) in one launch, grid (32,32,8)
struct TPtrs { const float* s[8]; unsigned short* d[8]; };
__global__ __launch_bounds__(256) void tcvt_batch_kernel(TPtrs p)
{
  __shared__ float tile[32][33];
  const float* __restrict__ src = p.s[blockIdx.z];
  unsigned short* __restrict__ dst = p.d[blockIdx.z];
  const int bx = blockIdx.x, by = blockIdx.y;
  const int tx = threadIdx.x & 31, ty = threadIdx.x >> 5;
#pragma unroll
  for (int i = 0; i < 4; ++i)
    tile[ty + i * 8][tx] = src[(size_t)(by * 32 + ty + i * 8) * 1024 + bx * 32 + tx];
  __syncthreads();
#pragma unroll
  for (int i = 0; i < 4; ++i)
    dst[(size_t)(bx * 32 + ty + i * 8) * 1024 + by * 32 + tx] = f2bf(tile[tx][ty + i * 8]);
}

__global__ void biasprep_kernel(const float* sq, const float* sk, const float* sv,
                                const float* ck, const float* cv,
                                float* bsa, float* bca)
{
  int i = blockIdx.x * 256 + threadIdx.x;
  if (i < 3072) bsa[i] = (i < 1024) ? sq[i] : (i < 2048 ? sk[i - 1024] : sv[i - 2048]);
  int j = i - 3072;
  if (j >= 0 && j < 2048) bca[j] = (j < 1024) ? ck[j] : cv[j - 1024];
}

// ---------------------------------------------------------------------------
extern "C" void kernel_launch(void* const* d_in, const int* in_sizes, int n_in,
                              void* d_out, int out_size, void* d_ws, size_t ws_size,
                              hipStream_t stream)
{
  const float* tgt  = (const float*)d_in[0];
  const float* memi = (const float*)d_in[1];
  const int*   mask = (const int*)d_in[2];
  const float* sa_wq = (const float*)d_in[3];  const float* sa_bq = (const float*)d_in[4];
  const float* sa_wk = (const float*)d_in[5];  const float* sa_bk = (const float*)d_in[6];
  const float* sa_wv = (const float*)d_in[7];  const float* sa_bv = (const float*)d_in[8];
  const float* sa_wo = (const float*)d_in[9];  const float* sa_bo = (const float*)d_in[10];
  const float* ca_wq = (const float*)d_in[11]; const float* ca_bq = (const float*)d_in[12];
  const float* ca_wk = (const float*)d_in[13]; const float* ca_bk = (const float*)d_in[14];
  const float* ca_wv = (const float*)d_in[15]; const float* ca_bv = (const float*)d_in[16];
  const float* ca_wo = (const float*)d_in[17]; const float* ca_bo = (const float*)d_in[18];
  const float* w1 = (const float*)d_in[19]; const float* b1 = (const float*)d_in[20];
  const float* w2 = (const float*)d_in[21]; const float* b2 = (const float*)d_in[22];
  const float* g1 = (const float*)d_in[23]; const float* be1 = (const float*)d_in[24];
  const float* g2 = (const float*)d_in[25]; const float* be2 = (const float*)d_in[26];
  const float* g3 = (const float*)d_in[27]; const float* be3 = (const float*)d_in[28];
  float* out = (float*)d_out;
  char* W = (char*)d_ws;
  const size_t MB = 1 << 20;
  typedef unsigned short us;

  // workspace layout (byte offsets, total 113 MB; stream order makes reuses safe)
  us* Wsaqkv = (us*)(W + 0);          // [3072][1024] bf16
  us* Wsao   = (us*)(W + 6 * MB);     // [1024][1024]
  us* Wcaq   = (us*)(W + 8 * MB);
  us* Wcakv  = (us*)(W + 10 * MB);    // [2048][1024]
  us* Wcao   = (us*)(W + 14 * MB);
  us* W1t    = (us*)(W + 16 * MB);    // [4096][1024]
  us* W2t    = (us*)(W + 24 * MB);    // [1024][4096]
  float* b_saqkv = (float*)(W + 32 * MB);            // 3072 f32
  float* b_cakv  = (float*)(W + 32 * MB + 16384);    // 2048 f32
  us* tgt_bf = (us*)(W + 33 * MB);    // 8MB; dead after SA-QKV gemm -> reused as T2b
  us* T2b    = tgt_bf;
  us* mem_bf = (us*)(W + 41 * MB);    // 8MB; dead after CA-KV gemm
  us* QKV    = (us*)(W + 49 * MB);    // SA: [4096][3072] bf16, 24MB
  us* Qca    = (us*)(W + 49 * MB);    // CA: [4096][1024], 8MB
  us* KVca   = (us*)(W + 57 * MB);    // CA: [4096][2048], 16MB
  us* T1b    = (us*)(W + 65 * MB);    // 8MB
  us* AO     = (us*)(W + 73 * MB);    // [4096][1024] bf16, 8MB
  us* Hb     = (us*)(W + 49 * MB);    // FFN hidden [4096][4096] bf16, 32MB (QKV/AO dead)
  float* Op  = (float*)(W + 81 * MB); // [4096][1024] f32, 16MB
  float* T1f = (float*)(W + 97 * MB); // 16MB; T2f aliases (in-place addln)
  float* T2f = T1f;

  const int M = 4096;
  dim3 blk(256);
  auto gemm = [&](const us* Aa, const us* Bta, const float* bias, void* Cc,
                  int Nn, int Kk, int flags) {
    gemm_bf16_kernel<<<dim3(Nn / 128, M / 128), blk, 0, stream>>>(Aa, Bta, bias, Cc, M, Nn, Kk, flags);
  };

  // ---- conversions (batched) ----
  TPtrs tp;
  tp.s[0] = sa_wq; tp.d[0] = Wsaqkv;
  tp.s[1] = sa_wk; tp.d[1] = Wsaqkv + 1024 * 1024;
  tp.s[2] = sa_wv; tp.d[2] = Wsaqkv + 2048 * 1024;
  tp.s[3] = sa_wo; tp.d[3] = Wsao;
  tp.s[4] = ca_wq; tp.d[4] = Wcaq;
  tp.s[5] = ca_wk; tp.d[5] = Wcakv;
  tp.s[6] = ca_wv; tp.d[6] = Wcakv + 1024 * 1024;
  tp.s[7] = ca_wo; tp.d[7] = Wcao;
  tcvt_batch_kernel<<<dim3(32, 32, 8), blk, 0, stream>>>(tp);
  transpose_cvt_kernel<<<dim3(128, 32), blk, 0, stream>>>(w1, W1t, 1024, 4096);
  transpose_cvt_kernel<<<dim3(32, 128), blk, 0, stream>>>(w2, W2t, 4096, 1024);
  cvt2_bf16_kernel<<<dim3(4096), blk, 0, stream>>>(tgt, memi, tgt_bf, mem_bf, M * 1024 / 8);
  biasprep_kernel<<<dim3(20), blk, 0, stream>>>(sa_bq, sa_bk, sa_bv, ca_bk, ca_bv, b_saqkv, b_cakv);

  // ---- self-attention ----
  gemm(tgt_bf, Wsaqkv, b_saqkv, QKV, 3072, 1024, 2);
  attn_kernel<<<dim3(16, 16, 4), blk, 0, stream>>>(QKV, QKV + 1024, QKV + 2048, 3072, 3072, mask, AO);
  gemm(AO, Wsao, sa_bo, Op, 1024, 1024, 0);
  addln_kernel<<<dim3(M), blk, 0, stream>>>(tgt, Op, g1, be1, T1f, T1b);

  // ---- cross-attention ----
  gemm(T1b, Wcaq, ca_bq, Qca, 1024, 1024, 2);
  gemm(mem_bf, Wcakv, b_cakv, KVca, 2048, 1024, 2);
  attn_kernel<<<dim3(16, 16, 4), blk, 0, stream>>>(Qca, KVca, KVca + 1024, 1024, 2048, mask, AO);
  gemm(AO, Wcao, ca_bo, Op, 1024, 1024, 0);
  addln_kernel<<<dim3(M), blk, 0, stream>>>(T1f, Op, g2, be2, T2f, T2b);

  // ---- FFN ----
  gemm(T2b, W1t, b1, Hb, 4096, 1024, 3);        // relu + bf16 out
  gemm(Hb, W2t, b2, Op, 1024, 4096, 0);
  addln_kernel<<<dim3(M), blk, 0, stream>>>(T2f, Op, g3, be3, out, nullptr);

  (void)in_sizes; (void)n_in; (void)out_size; (void)ws_size; (void)mask;
}